// Round 6
// baseline (282.384 us; speedup 1.0000x reference)
//
#include <hip/hip_runtime.h>

#define SS 4096
#define DD 1024
#define LL 16
#define ROWF 1028   // LDS row stride in floats (4 KB + 16 B pad)

typedef __attribute__((ext_vector_type(8))) short short8;
typedef __attribute__((ext_vector_type(4))) float fl4;

static __device__ __forceinline__ short f2bf(float f) {
    // round-to-nearest-even fp32 -> bf16 (inputs finite)
    unsigned u = __float_as_uint(f);
    u += 0x7FFFu + ((u >> 16) & 1u);
    return (short)(u >> 16);
}

static __device__ __forceinline__ short8 pack8(fl4 a, fl4 b) {
    short8 r;
    r[0] = f2bf(a[0]); r[1] = f2bf(a[1]); r[2] = f2bf(a[2]); r[3] = f2bf(a[3]);
    r[4] = f2bf(b[0]); r[5] = f2bf(b[1]); r[6] = f2bf(b[2]); r[7] = f2bf(b[3]);
    return r;
}

// Async global->LDS DMA: 16B/lane, per-lane src addr, dest = uniform base + lane*16.
static __device__ __forceinline__ void dma16(const float* g, float* l) {
    __builtin_amdgcn_global_load_lds(
        (const __attribute__((address_space(1))) void*)g,
        (__attribute__((address_space(3))) void*)l, 16, 0, 0);
}

// 512 blocks x 512 thr, 2 BLOCKS/CU (LDS 74.3 KB/block) -> 4 waves/SIMD.
// TLP is the pipeline: when one block stalls at vmcnt/s_barrier, the co-resident
// block's waves run. Each block owns (b, 64-s segment) = 8 granules of 8 s,
// 2 LDS buffers, depth-1 prefetch, PV deferred one granule (fronts the wait).
// Iter g:
//   PV(g-1) from buf[(g-1)&1] + e_lds        (pure LDS+VALU, no waits)
//   lgkm(0) + Bpv   (PV reads done -> buf[(g+1)&1] free)
//   DMA(g+1) -> buf[(g+1)&1]
//   vmcnt(4|0)      (granule g landed; g+1 stays in flight)
//   B1              (granule g visible cross-wave)
//   scores(g): 4 x mfma_16x16x32_bf16 per wave (K=128 slice)
//   scr -> lgkm+B2 -> softmax (threads 0..127, one (s,l)) -> e_lds, z -> lgkm+B3
// Epilogue: PV(7); part/Zpart stores.
// MFMA D layout: col(s)=lane&15, row(l)=(lane>>4)*4+reg  [m89-verified]
__global__ __launch_bounds__(512, 4) void k_main(const float* __restrict__ mem,
                                                 const float* __restrict__ summ,
                                                 float* __restrict__ part,
                                                 float* __restrict__ Zpart) {
    __shared__ float buf[2][8 * ROWF];    // 65.8 KB
    __shared__ float e_lds[8 * LL];       // 0.5 KB
    __shared__ float scr[8][256];         // 8 KB

    int blk = blockIdx.x;                 // 512 = 8 b x 64 segments
    int b   = blk >> 6;
    int s_base = (blk & 63) << 6;         // 64 s per block
    int t    = threadIdx.x;
    int wv   = t >> 6;                    // 0..7
    int lane = t & 63;
    int o  = lane & 15;
    int qd = lane >> 4;

    const float* gseg = mem + ((size_t)b * SS + s_base) * DD;

    // summ loads FIRST (consumed by pack8 before DMA waits matter)
    fl4 a0[4], a1[4];
    {
        const float* arow = summ + o * DD + wv * 128 + qd * 8;
        #pragma unroll
        for (int j = 0; j < 4; ++j) {
            a0[j] = *(const fl4*)(arow + j * 32);
            a1[j] = *(const fl4*)(arow + j * 32 + 4);
        }
    }
    short8 afr[4];
    #pragma unroll
    for (int j = 0; j < 4; ++j) afr[j] = pack8(a0[j], a1[j]);

    // Prologue: DMA granule 0 (wave's share: row wv, 4 x 1KB chunks)
    #pragma unroll
    for (int c = 0; c < 4; ++c)
        dma16(gseg + (size_t)wv * DD + c * 256 + lane * 4,
              &buf[0][wv * ROWF + c * 256]);

    int lg = t >> 8;                      // l-group: 0 -> l=0..7, 1 -> l=8..15
    int q  = t & 255;                     // owned d-quad
    // softmax role (threads 0..127): s_sm = t&7, l_sm = (t>>3)&15
    int s_sm = t & 7;
    int l_sm = (t >> 3) & 15;
    int scr_idx = ((l_sm >> 2) * 16 + s_sm) * 4 + (l_sm & 3);  // scr[.][lane'*4+reg]

    fl4 ctx[8];
    #pragma unroll
    for (int l = 0; l < 8; ++l) ctx[l] = (fl4){0.f, 0.f, 0.f, 0.f};
    float z = 0.f;                        // per-thread Z partial (threads <128)
    const float scale = 0.03125f;         // 1/sqrt(1024)

    for (int g = 0; g < 8; ++g) {
        // ---- PV(g-1): fronts the fetch wait; pure LDS + VALU ----
        if (g > 0) {
            const float* mrow = &buf[(g - 1) & 1][0] + q * 4;
            const fl4* erow = (const fl4*)&e_lds[lg * 8];
            #pragma unroll
            for (int s = 0; s < 8; ++s) {
                fl4 m4 = *(const fl4*)(mrow + s * ROWF);
                fl4 e0 = erow[s * 4];     // e_lds[s*16 + lg*8 .. +3] (broadcast)
                fl4 e1 = erow[s * 4 + 1]; // e_lds[s*16 + lg*8+4 .. +7]
                #pragma unroll
                for (int j = 0; j < 4; ++j) {
                    ctx[j]     += e0[j] * m4;
                    ctx[4 + j] += e1[j] * m4;
                }
            }
        }
        asm volatile("s_waitcnt lgkmcnt(0)" ::: "memory");
        __builtin_amdgcn_sched_barrier(0);
        __builtin_amdgcn_s_barrier();     // Bpv: buf[(g+1)&1] free for DMA
        __builtin_amdgcn_sched_barrier(0);

        if (g < 7) {                      // DMA(g+1) into the freed buffer
            const float* gp = gseg + (size_t)(g + 1) * 8 * DD;
            float* nb = &buf[(g + 1) & 1][wv * ROWF];
            dma16(gp + (size_t)wv * DD +   0 + lane * 4, nb +   0);
            dma16(gp + (size_t)wv * DD + 256 + lane * 4, nb + 256);
            dma16(gp + (size_t)wv * DD + 512 + lane * 4, nb + 512);
            dma16(gp + (size_t)wv * DD + 768 + lane * 4, nb + 768);
            asm volatile("s_waitcnt vmcnt(4)" ::: "memory");  // granule g landed
        } else {
            asm volatile("s_waitcnt vmcnt(0)" ::: "memory");
        }
        __builtin_amdgcn_sched_barrier(0);
        __builtin_amdgcn_s_barrier();     // B1: granule g visible cross-wave
        __builtin_amdgcn_sched_barrier(0);

        // ---- scores(g): this wave's K=128 slice; rows o&7 (cols 8-15 dup) ----
        const float* bbase = &buf[g & 1][0];
        fl4 acc = {0.f, 0.f, 0.f, 0.f};
        const float* brow = bbase + (o & 7) * ROWF + wv * 128 + qd * 8;
        #pragma unroll
        for (int j = 0; j < 4; ++j) {
            fl4 f0 = *(const fl4*)(brow + j * 32);
            fl4 f1 = *(const fl4*)(brow + j * 32 + 4);
            acc = __builtin_amdgcn_mfma_f32_16x16x32_bf16(afr[j], pack8(f0, f1),
                                                          acc, 0, 0, 0);
        }
        *(fl4*)&scr[wv][lane * 4] = acc;
        asm volatile("s_waitcnt lgkmcnt(0)" ::: "memory");
        __builtin_amdgcn_s_barrier();     // B2: partials visible
        __builtin_amdgcn_sched_barrier(0);

        // ---- softmax: threads 0..127, one (s,l) each ----
        if (t < 128) {
            float sum = 0.f;
            #pragma unroll
            for (int w8 = 0; w8 < 8; ++w8) sum += scr[w8][scr_idx];
            float ev = __expf(sum * scale);
            e_lds[s_sm * LL + l_sm] = ev;
            z += ev;
        }
        asm volatile("s_waitcnt lgkmcnt(0)" ::: "memory");
        __builtin_amdgcn_s_barrier();     // B3: e_lds ready for PV next iter
        __builtin_amdgcn_sched_barrier(0);
    }

    // ---- epilogue PV(7) ----
    {
        const float* mrow = &buf[7 & 1][0] + q * 4;
        const fl4* erow = (const fl4*)&e_lds[lg * 8];
        #pragma unroll
        for (int s = 0; s < 8; ++s) {
            fl4 m4 = *(const fl4*)(mrow + s * ROWF);
            fl4 e0 = erow[s * 4];
            fl4 e1 = erow[s * 4 + 1];
            #pragma unroll
            for (int j = 0; j < 4; ++j) {
                ctx[j]     += e0[j] * m4;
                ctx[4 + j] += e1[j] * m4;
            }
        }
    }

    // Unnormalized ctx partials; layout = [blk][l][d]  (512 x 16 x 1024 fp32)
    float* pp = part + (size_t)blk * LL * DD + (size_t)(lg * 8) * DD + q * 4;
    #pragma unroll
    for (int l = 0; l < 8; ++l) *(fl4*)(pp + (size_t)l * DD) = ctx[l];

    // Z: threads 0..127 hold z for (s_sm, l_sm); reduce over s (xor 1,2,4);
    // lane with s_sm==0 writes Zpart[blk*16 + l_sm]
    if (t < 128) {
        float v = z;
        v += __shfl_xor(v, 1, 64);
        v += __shfl_xor(v, 2, 64);
        v += __shfl_xor(v, 4, 64);
        if (s_sm == 0) Zpart[blk * LL + l_sm] = v;
    }
}

// out[b][d] = sum_l (w[l] / sum_seg Zpart) * sum_seg part[b*64+seg][l][d]
// 256 blocks x 256 thr; fl4 loads (16B/lane); 64 segs, 2 per thread
__global__ __launch_bounds__(256) void k_out(const float* __restrict__ part,
                                             const float* __restrict__ Zpart,
                                             const float* __restrict__ w,
                                             float* __restrict__ out) {
    int blkid = blockIdx.x;          // 256 = 8 b x 32 d-chunks of 32
    int b  = blkid >> 5;
    int d0 = (blkid & 31) << 5;
    int t = threadIdx.x;
    __shared__ float coef[LL];
    __shared__ fl4 red[32][8];       // [thread-group][d-quad]

    if (t < LL) {
        float Z = 0.f;
        #pragma unroll
        for (int s = 0; s < 64; ++s) Z += Zpart[(b * 64 + s) * LL + t];
        coef[t] = w[t] / Z;
    }
    __syncthreads();

    int dq = t & 7;                  // d-quad within 32-d chunk
    int sg = t >> 3;                 // 0..31; handles segs sg and sg+32
    fl4 acc = {0.f, 0.f, 0.f, 0.f};
    #pragma unroll
    for (int h = 0; h < 2; ++h) {
        const float* pb = part + (size_t)(b * 64 + sg + h * 32) * LL * DD + d0 + dq * 4;
        #pragma unroll
        for (int l = 0; l < LL; ++l) {
            fl4 v = *(const fl4*)(pb + (size_t)l * DD);
            acc += coef[l] * v;
        }
    }
    red[sg][dq] = acc;
    __syncthreads();

    if (t < 8) {
        fl4 s = {0.f, 0.f, 0.f, 0.f};
        #pragma unroll
        for (int g = 0; g < 32; ++g) s += red[g][t];
        *(fl4*)&out[b * DD + d0 + t * 4] = s;
    }
}

extern "C" void kernel_launch(void* const* d_in, const int* in_sizes, int n_in,
                              void* d_out, int out_size, void* d_ws, size_t ws_size,
                              hipStream_t stream) {
    const float* mem  = (const float*)d_in[0];  // [8,4096,1024] fp32
    const float* summ = (const float*)d_in[1];  // [16,1024] fp32
    const float* w    = (const float*)d_in[2];  // [1,16] fp32
    float* out = (float*)d_out;                 // [8,1024] fp32

    char* ws = (char*)d_ws;
    float* Zpart = (float*)ws;                  // 512*16 fl = 32 KB (pad to 64K)
    float* part  = (float*)(ws + 64 * 1024);    // 512*16*1024 fl = 32 MB

    k_main<<<512, 512, 0, stream>>>(mem, summ, part, Zpart);
    k_out<<<256, 256, 0, stream>>>(part, Zpart, w, out);
}

// Round 7
// 209.255 us; speedup vs baseline: 1.3495x; 1.3495x over previous
//
#include <hip/hip_runtime.h>

#define SS 4096
#define DD 1024
#define LL 16
#define ROWF 1028   // LDS row stride in floats (4 KB + 16 B pad)

typedef __attribute__((ext_vector_type(8))) short short8;
typedef __attribute__((ext_vector_type(4))) float fl4;

static __device__ __forceinline__ short f2bf(float f) {
    // round-to-nearest-even fp32 -> bf16 (inputs finite)
    unsigned u = __float_as_uint(f);
    u += 0x7FFFu + ((u >> 16) & 1u);
    return (short)(u >> 16);
}

static __device__ __forceinline__ short8 pack8(fl4 a, fl4 b) {
    short8 r;
    r[0] = f2bf(a[0]); r[1] = f2bf(a[1]); r[2] = f2bf(a[2]); r[3] = f2bf(a[3]);
    r[4] = f2bf(b[0]); r[5] = f2bf(b[1]); r[6] = f2bf(b[2]); r[7] = f2bf(b[3]);
    return r;
}

// Async global->LDS DMA: 16B/lane, per-lane src addr, dest = uniform base + lane*16.
static __device__ __forceinline__ void dma16(const float* g, float* l) {
    __builtin_amdgcn_global_load_lds(
        (const __attribute__((address_space(1))) void*)g,
        (__attribute__((address_space(3))) void*)l, 16, 0, 0);
}

// 512 blocks x 512 thr. LDS = 74.3 KB/block -> 2 blocks/CU *by LDS*; VGPRs
// must stay <=128 for 4 waves/SIMD. NO min-waves clamp in __launch_bounds__:
// R6's (512,4) forced 64 VGPRs -> ~310 MB scratch spill traffic/dispatch
// (WRITE_SIZE 240 MB, FETCH 233 MB) and 2x regression. Compiler's natural
// allocation (~90-110) fits the 128 budget without spills.
// TLP is the pipeline: when one block stalls at vmcnt/s_barrier, the
// co-resident block's waves issue. Each block: (b, 64-s segment) = 8 granules
// of 8 s, 2 LDS buffers, depth-1 prefetch, PV deferred one granule.
// Iter g:
//   PV(g-1) from buf[(g-1)&1] + e_lds        (pure LDS+VALU, no waits)
//   lgkm(0) + Bpv   (PV reads done -> buf[(g+1)&1] free)
//   DMA(g+1) -> buf[(g+1)&1]
//   vmcnt(4|0)      (granule g landed; g+1 stays in flight)
//   B1              (granule g visible cross-wave)
//   scores(g): 4 x mfma_16x16x32_bf16 per wave (K=128 slice)
//   scr -> lgkm+B2 -> softmax (threads 0..127, one (s,l)) -> e_lds, z -> lgkm+B3
// Epilogue: PV(7); part/Zpart stores.
// MFMA D layout: col(s)=lane&15, row(l)=(lane>>4)*4+reg  [m89-verified]
__global__ __launch_bounds__(512) void k_main(const float* __restrict__ mem,
                                              const float* __restrict__ summ,
                                              float* __restrict__ part,
                                              float* __restrict__ Zpart) {
    __shared__ float buf[2][8 * ROWF];    // 65.8 KB
    __shared__ float e_lds[8 * LL];       // 0.5 KB
    __shared__ float scr[8][256];         // 8 KB

    int blk = blockIdx.x;                 // 512 = 8 b x 64 segments
    int b   = blk >> 6;
    int s_base = (blk & 63) << 6;         // 64 s per block
    int t    = threadIdx.x;
    int wv   = t >> 6;                    // 0..7
    int lane = t & 63;
    int o  = lane & 15;
    int qd = lane >> 4;

    const float* gseg = mem + ((size_t)b * SS + s_base) * DD;

    // summ loads FIRST (consumed by pack8 before DMA waits matter)
    fl4 a0[4], a1[4];
    {
        const float* arow = summ + o * DD + wv * 128 + qd * 8;
        #pragma unroll
        for (int j = 0; j < 4; ++j) {
            a0[j] = *(const fl4*)(arow + j * 32);
            a1[j] = *(const fl4*)(arow + j * 32 + 4);
        }
    }
    short8 afr[4];
    #pragma unroll
    for (int j = 0; j < 4; ++j) afr[j] = pack8(a0[j], a1[j]);

    // Prologue: DMA granule 0 (wave's share: row wv, 4 x 1KB chunks)
    #pragma unroll
    for (int c = 0; c < 4; ++c)
        dma16(gseg + (size_t)wv * DD + c * 256 + lane * 4,
              &buf[0][wv * ROWF + c * 256]);

    int lg = t >> 8;                      // l-group: 0 -> l=0..7, 1 -> l=8..15
    int q  = t & 255;                     // owned d-quad
    // softmax role (threads 0..127): s_sm = t&7, l_sm = (t>>3)&15
    int s_sm = t & 7;
    int l_sm = (t >> 3) & 15;
    int scr_idx = ((l_sm >> 2) * 16 + s_sm) * 4 + (l_sm & 3);  // scr[.][lane'*4+reg]

    fl4 ctx[8];
    #pragma unroll
    for (int l = 0; l < 8; ++l) ctx[l] = (fl4){0.f, 0.f, 0.f, 0.f};
    float z = 0.f;                        // per-thread Z partial (threads <128)
    const float scale = 0.03125f;         // 1/sqrt(1024)

    for (int g = 0; g < 8; ++g) {
        // ---- PV(g-1): fronts the fetch wait; pure LDS + VALU ----
        if (g > 0) {
            const float* mrow = &buf[(g - 1) & 1][0] + q * 4;
            const fl4* erow = (const fl4*)&e_lds[lg * 8];
            #pragma unroll
            for (int s = 0; s < 8; ++s) {
                fl4 m4 = *(const fl4*)(mrow + s * ROWF);
                fl4 e0 = erow[s * 4];     // e_lds[s*16 + lg*8 .. +3] (broadcast)
                fl4 e1 = erow[s * 4 + 1]; // e_lds[s*16 + lg*8+4 .. +7]
                #pragma unroll
                for (int j = 0; j < 4; ++j) {
                    ctx[j]     += e0[j] * m4;
                    ctx[4 + j] += e1[j] * m4;
                }
            }
        }
        asm volatile("s_waitcnt lgkmcnt(0)" ::: "memory");
        __builtin_amdgcn_sched_barrier(0);
        __builtin_amdgcn_s_barrier();     // Bpv: buf[(g+1)&1] free for DMA
        __builtin_amdgcn_sched_barrier(0);

        if (g < 7) {                      // DMA(g+1) into the freed buffer
            const float* gp = gseg + (size_t)(g + 1) * 8 * DD;
            float* nb = &buf[(g + 1) & 1][wv * ROWF];
            dma16(gp + (size_t)wv * DD +   0 + lane * 4, nb +   0);
            dma16(gp + (size_t)wv * DD + 256 + lane * 4, nb + 256);
            dma16(gp + (size_t)wv * DD + 512 + lane * 4, nb + 512);
            dma16(gp + (size_t)wv * DD + 768 + lane * 4, nb + 768);
            asm volatile("s_waitcnt vmcnt(4)" ::: "memory");  // granule g landed
        } else {
            asm volatile("s_waitcnt vmcnt(0)" ::: "memory");
        }
        __builtin_amdgcn_sched_barrier(0);
        __builtin_amdgcn_s_barrier();     // B1: granule g visible cross-wave
        __builtin_amdgcn_sched_barrier(0);

        // ---- scores(g): this wave's K=128 slice; rows o&7 (cols 8-15 dup) ----
        const float* bbase = &buf[g & 1][0];
        fl4 acc = {0.f, 0.f, 0.f, 0.f};
        const float* brow = bbase + (o & 7) * ROWF + wv * 128 + qd * 8;
        #pragma unroll
        for (int j = 0; j < 4; ++j) {
            fl4 f0 = *(const fl4*)(brow + j * 32);
            fl4 f1 = *(const fl4*)(brow + j * 32 + 4);
            acc = __builtin_amdgcn_mfma_f32_16x16x32_bf16(afr[j], pack8(f0, f1),
                                                          acc, 0, 0, 0);
        }
        *(fl4*)&scr[wv][lane * 4] = acc;
        asm volatile("s_waitcnt lgkmcnt(0)" ::: "memory");
        __builtin_amdgcn_s_barrier();     // B2: partials visible
        __builtin_amdgcn_sched_barrier(0);

        // ---- softmax: threads 0..127, one (s,l) each ----
        if (t < 128) {
            float sum = 0.f;
            #pragma unroll
            for (int w8 = 0; w8 < 8; ++w8) sum += scr[w8][scr_idx];
            float ev = __expf(sum * scale);
            e_lds[s_sm * LL + l_sm] = ev;
            z += ev;
        }
        asm volatile("s_waitcnt lgkmcnt(0)" ::: "memory");
        __builtin_amdgcn_s_barrier();     // B3: e_lds ready for PV next iter
        __builtin_amdgcn_sched_barrier(0);
    }

    // ---- epilogue PV(7) ----
    {
        const float* mrow = &buf[7 & 1][0] + q * 4;
        const fl4* erow = (const fl4*)&e_lds[lg * 8];
        #pragma unroll
        for (int s = 0; s < 8; ++s) {
            fl4 m4 = *(const fl4*)(mrow + s * ROWF);
            fl4 e0 = erow[s * 4];
            fl4 e1 = erow[s * 4 + 1];
            #pragma unroll
            for (int j = 0; j < 4; ++j) {
                ctx[j]     += e0[j] * m4;
                ctx[4 + j] += e1[j] * m4;
            }
        }
    }

    // Unnormalized ctx partials; layout = [blk][l][d]  (512 x 16 x 1024 fp32)
    float* pp = part + (size_t)blk * LL * DD + (size_t)(lg * 8) * DD + q * 4;
    #pragma unroll
    for (int l = 0; l < 8; ++l) *(fl4*)(pp + (size_t)l * DD) = ctx[l];

    // Z: threads 0..127 hold z for (s_sm, l_sm); reduce over s (xor 1,2,4);
    // lane with s_sm==0 writes Zpart[blk*16 + l_sm]
    if (t < 128) {
        float v = z;
        v += __shfl_xor(v, 1, 64);
        v += __shfl_xor(v, 2, 64);
        v += __shfl_xor(v, 4, 64);
        if (s_sm == 0) Zpart[blk * LL + l_sm] = v;
    }
}

// out[b][d] = sum_l (w[l] / sum_seg Zpart) * sum_seg part[b*64+seg][l][d]
// 256 blocks x 256 thr; fl4 loads (16B/lane); 64 segs, 2 per thread
__global__ __launch_bounds__(256) void k_out(const float* __restrict__ part,
                                             const float* __restrict__ Zpart,
                                             const float* __restrict__ w,
                                             float* __restrict__ out) {
    int blkid = blockIdx.x;          // 256 = 8 b x 32 d-chunks of 32
    int b  = blkid >> 5;
    int d0 = (blkid & 31) << 5;
    int t = threadIdx.x;
    __shared__ float coef[LL];
    __shared__ fl4 red[32][8];       // [thread-group][d-quad]

    if (t < LL) {
        float Z = 0.f;
        #pragma unroll
        for (int s = 0; s < 64; ++s) Z += Zpart[(b * 64 + s) * LL + t];
        coef[t] = w[t] / Z;
    }
    __syncthreads();

    int dq = t & 7;                  // d-quad within 32-d chunk
    int sg = t >> 3;                 // 0..31; handles segs sg and sg+32
    fl4 acc = {0.f, 0.f, 0.f, 0.f};
    #pragma unroll
    for (int h = 0; h < 2; ++h) {
        const float* pb = part + (size_t)(b * 64 + sg + h * 32) * LL * DD + d0 + dq * 4;
        #pragma unroll
        for (int l = 0; l < LL; ++l) {
            fl4 v = *(const fl4*)(pb + (size_t)l * DD);
            acc += coef[l] * v;
        }
    }
    red[sg][dq] = acc;
    __syncthreads();

    if (t < 8) {
        fl4 s = {0.f, 0.f, 0.f, 0.f};
        #pragma unroll
        for (int g = 0; g < 32; ++g) s += red[g][t];
        *(fl4*)&out[b * DD + d0 + t * 4] = s;
    }
}

extern "C" void kernel_launch(void* const* d_in, const int* in_sizes, int n_in,
                              void* d_out, int out_size, void* d_ws, size_t ws_size,
                              hipStream_t stream) {
    const float* mem  = (const float*)d_in[0];  // [8,4096,1024] fp32
    const float* summ = (const float*)d_in[1];  // [16,1024] fp32
    const float* w    = (const float*)d_in[2];  // [1,16] fp32
    float* out = (float*)d_out;                 // [8,1024] fp32

    char* ws = (char*)d_ws;
    float* Zpart = (float*)ws;                  // 512*16 fl = 32 KB (pad to 64K)
    float* part  = (float*)(ws + 64 * 1024);    // 512*16*1024 fl = 32 MB

    k_main<<<512, 512, 0, stream>>>(mem, summ, part, Zpart);
    k_out<<<256, 256, 0, stream>>>(part, Zpart, w, out);
}